// Round 9
// baseline (221.061 us; speedup 1.0000x reference)
//
#include <hip/hip_runtime.h>

// ---------------------------------------------------------------------------
// R_SCNN: two width-direction SCNN scans fused into one 127-step recurrence,
// executed with MFMA, then 4x bilinear upsample + global BN + sigmoid.
//
//   y_w = c_w + relu(M y_{w-1}),  z_w = y_w + relu(M z_{w-1}),  z_0 = y_0 = c_0
//   s[b,h,p] = dot(v, z_{127-p});  out = sigmoid(BN(upsample4(s)))
//
// Round-13: ONE mega-kernel. R1/R6/R8 all show a stable ~72.6us outside the
// scan -- mostly per-dispatch overhead (3 launches) + k_norm's bilin
// recompute. Fusion: 256 blocks x 512 threads; phases extract -> scan
// (blocks 0-127) -> stats -> norm, separated by global barriers.
// Why this is safe where R7's fused epilogue wasn't:
//  - only tid0 of each block polls (256 pollers via coherent atomicAdd(c,0)
//    + s_sleep), not 65536 volatile-spinners;
//  - LDS padded to 82KB -> exactly 1 block/CU, grid = 256 = #CUs -> all
//    blocks co-resident by construction (no deadlock window);
//  - release: __syncthreads drains vmcnt (writes reach L2), tid0
//    __threadfence does cache-global wbl2/inv; Md and s are replay-
//    invariant so stale lines are value-correct; stats (replay-varying)
//    is read via atomic + LDS broadcast;
//  - counters zeroed by host hipMemsetAsync (stream-ordered, capture-safe).
// Scan body is byte-identical to R8's measured 103.5us version. Phase 3
// keeps its 2 bilin values in registers across the barrier (no recompute).
// ---------------------------------------------------------------------------

typedef _Float16 f16x8 __attribute__((ext_vector_type(8)));
typedef _Float16 f16x4 __attribute__((ext_vector_type(4)));
typedef float    f32x4 __attribute__((ext_vector_type(4)));

// Raw workgroup barrier: drain LDS ops only; global (vmcnt) loads stay in
// flight across it.
static __device__ __forceinline__ void sync_lds() {
  asm volatile("s_waitcnt lgkmcnt(0)" ::: "memory");
  __builtin_amdgcn_s_barrier();
  asm volatile("" ::: "memory");
}

// quad_perm(0,0,2,2): lane 2k+1 receives lane 2k's value (VALU-speed, no LDS)
static __device__ __forceinline__ float dpp_even(float v) {
  int t = __builtin_bit_cast(int, v);
  t = __builtin_amdgcn_update_dpp(t, t, 0xA0, 0xF, 0xF, false);
  return __builtin_bit_cast(float, t);
}

// Grid barrier: one arrival + one poller per block. __syncthreads drains the
// block's outstanding stores into L2; tid0's __threadfence flushes/invalidates
// cache-globally (wbl2/inv are cache-wide ops on gfx950).
static __device__ __forceinline__ void gbar(int* c, int tid, int nblk) {
  __syncthreads();
  if (tid == 0) {
    __threadfence();                 // release: block's writes device-visible
    atomicAdd(c, 1);
    while (atomicAdd(c, 0) < nblk) __builtin_amdgcn_s_sleep(32);
    __threadfence();                 // acquire: drop stale cached lines
  }
  __syncthreads();
}

// ---- bilinear 4x upsample (align_corners) of s: (2,64,128) -> (2,256,512) --
static __device__ __forceinline__ float bilin(const float* __restrict__ s,
                                              int idx) {
  int bb  = idx >> 17;
  int rem = idx & 131071;
  int ho  = rem >> 9;
  int wo  = rem & 511;
  const float SY = 63.0f / 255.0f, SX = 127.0f / 511.0f;
  float fy = (float)ho * SY;
  int y0 = (int)fy; int y1 = min(y0 + 1, 63); float wy = fy - (float)y0;
  float fx = (float)wo * SX;
  int x0 = (int)fx; int x1 = min(x0 + 1, 127); float wx = fx - (float)x0;
  const float* sb = s + bb * 8192;
  float cA = sb[y0 * 128 + x0] * (1.f - wy) + sb[y1 * 128 + x0] * wy;
  float cB = sb[y0 * 128 + x1] * (1.f - wy) + sb[y1 * 128 + x1] * wy;
  return cA * (1.f - wx) + cB * wx;
}

// LDS: scan state + pad to >80KB so occupancy is exactly 1 block/CU
// (160KB/CU; 82KB forbids 2 blocks). 256 blocks on 256 CUs => co-resident.
struct SM {
  _Float16 cy[2][256];     // y carry (f16), ping-pong            [byte 0)
  _Float16 pad_[32];       // 64B: shifts z rows' banks by 16 vs cy
  _Float16 zh[128 * 256];  // z history; row w = z_w (also z carry)
  _Float16 pad2[7680];     // pad to 81984 B -> 1 block/CU
};

extern "C" __global__ void __launch_bounds__(512, 1)
k_fused(const float* __restrict__ p2, const float* __restrict__ convw,
        const float* __restrict__ conv1, const float* __restrict__ gamma,
        const float* __restrict__ beta, float* __restrict__ out,
        _Float16* __restrict__ Md, float* __restrict__ sout,
        float* __restrict__ stats, int* __restrict__ cnt) {
  __shared__ SM sm;
  __shared__ float ls[8], lq[8], sb2[2];
  const int tid = threadIdx.x;

  // ---- phase 1: extract center tap of conv_w -> dense f16 [o][c] ----------
  {
    int q = blockIdx.x * 512 + tid;         // 131072 of 147456 float4s
#pragma unroll 1
    for (int pass = 0; pass < 2; ++pass) {
      if (pass == 0 || q < 16384) {
        int qq = pass == 0 ? q : 131072 + q;
        float4 v = ((const float4*)convw)[qq];
        float vv[4] = {v.x, v.y, v.z, v.w};
        int f = qq * 4;
#pragma unroll
        for (int e = 0; e < 4; ++e) {
          int flat = f + e;                 // flat = idx*9 + 4 <=> center tap
          if (flat % 9 == 4) Md[flat / 9] = (_Float16)vv[e];
        }
      }
    }
  }
  gbar(cnt + 0, tid, 256);

  // ---- phase 2: fused double scan via MFMA (blocks 0..127) ----------------
  if (blockIdx.x < 128) {
    const int l    = tid & 63;
    const int r    = tid >> 6;        // wave 0..7
    const int col  = l & 15;          // MFMA n / A-row-within-tile index
    const int quad = l >> 4;          // MFMA k-group / C-row-group index
    const int b    = blockIdx.x >> 6;
    const int h    = blockIdx.x & 63;

    const bool isY   = (col == 0);
    const bool isZ   = (col == 1);
    const bool zlane = (l & 1);

    const int m0 = (r * 2 + 0) * 16 + quad * 4;
    const int m1 = (r * 2 + 1) * 16 + quad * 4;

    f16x8 A0[8], A1[8];
#pragma unroll
    for (int ch = 0; ch < 8; ++ch) {
      A0[ch] = *(const f16x8*)(Md + ((r*2+0)*16 + col) * 256 + ch*32 + quad*8);
      A1[ch] = *(const f16x8*)(Md + ((r*2+1)*16 + col) * 256 + ch*32 + quad*8);
    }

    const float* pbase = p2 + (size_t)b * 2097152 + (size_t)h * 128;

    float4 pA[4], pB[4], qA[4], qB[4];
    if (isY) {
#pragma unroll
      for (int i = 0; i < 4; ++i) {
        pA[i] = *(const float4*)(pbase + (size_t)(m0 + i) * 8192);
        pB[i] = *(const float4*)(pbase + (size_t)(m1 + i) * 8192);
        qA[i] = *(const float4*)(pbase + (size_t)(m0 + i) * 8192 + 4);
        qB[i] = *(const float4*)(pbase + (size_t)(m1 + i) * 8192 + 4);
      }
    }

    if (isY) {
      f16x4 pa, pb;
#pragma unroll
      for (int i = 0; i < 4; ++i) {
        pa[i] = (_Float16)pA[i].x; pb[i] = (_Float16)pB[i].x;
      }
      *(f16x4*)(sm.cy[0] + m0) = pa; *(f16x4*)(sm.cy[0] + m1) = pb;
      *(f16x4*)(sm.zh    + m0) = pa; *(f16x4*)(sm.zh    + m1) = pb;
    }
    sync_lds();

    const _Float16* pY0 = sm.cy[0] + quad * 8;
    const _Float16* pY1 = sm.cy[1] + quad * 8;
    const _Float16* zrd = sm.zh + quad * 8;
    _Float16*       zwr = sm.zh + 256;

#define STEP(PY, WY, CA, CB, COMP)                                             \
  do {                                                                         \
    const _Float16* bsrc = zlane ? zrd : (PY);                                 \
    f16x8 B[8];                                                                \
    _Pragma("unroll")                                                          \
    for (int ch = 0; ch < 8; ++ch)                                             \
      B[ch] = *(const f16x8*)(bsrc + ch * 32);                                 \
    f32x4 a00 = {0.f,0.f,0.f,0.f}, a01 = {0.f,0.f,0.f,0.f};                    \
    f32x4 a10 = {0.f,0.f,0.f,0.f}, a11 = {0.f,0.f,0.f,0.f};                    \
    _Pragma("unroll")                                                          \
    for (int ch = 0; ch < 4; ++ch) {                                           \
      a00 = __builtin_amdgcn_mfma_f32_16x16x32_f16(A0[ch],   B[ch],   a00,0,0,0);\
      a10 = __builtin_amdgcn_mfma_f32_16x16x32_f16(A1[ch],   B[ch],   a10,0,0,0);\
      a01 = __builtin_amdgcn_mfma_f32_16x16x32_f16(A0[ch+4], B[ch+4], a01,0,0,0);\
      a11 = __builtin_amdgcn_mfma_f32_16x16x32_f16(A1[ch+4], B[ch+4], a11,0,0,0);\
    }                                                                          \
    f32x4 acc0 = a00 + a01, acc1 = a10 + a11;                                  \
    f32x4 yf0 = {}, yf1 = {};                                                  \
    if (isY) {                                                                 \
      f16x4 yh0, yh1;                                                          \
      _Pragma("unroll")                                                        \
      for (int i = 0; i < 4; ++i) {                                            \
        yf0[i] = (CA)[i].COMP + fmaxf(acc0[i], 0.f);                           \
        yf1[i] = (CB)[i].COMP + fmaxf(acc1[i], 0.f);                           \
        yh0[i] = (_Float16)yf0[i]; yh1[i] = (_Float16)yf1[i];                  \
      }                                                                        \
      *(f16x4*)((WY) + m0) = yh0;                                              \
      *(f16x4*)((WY) + m1) = yh1;                                              \
    }                                                                          \
    _Pragma("unroll")                                                          \
    for (int i = 0; i < 4; ++i) {                                              \
      yf0[i] = dpp_even(yf0[i]);                                               \
      yf1[i] = dpp_even(yf1[i]);                                               \
    }                                                                          \
    if (isZ) {                                                                 \
      f16x4 zh0, zh1;                                                          \
      _Pragma("unroll")                                                        \
      for (int i = 0; i < 4; ++i) {                                            \
        zh0[i] = (_Float16)(yf0[i] + fmaxf(acc0[i], 0.f));                     \
        zh1[i] = (_Float16)(yf1[i] + fmaxf(acc1[i], 0.f));                     \
      }                                                                        \
      *(f16x4*)(zwr + m0) = zh0;                                               \
      *(f16x4*)(zwr + m1) = zh1;                                               \
    }                                                                          \
    zrd += 256; zwr += 256;                                                    \
    sync_lds();                                                                \
  } while (0)

#define REFILL(SA, SB, W0)                                                     \
  do {                                                                         \
    if (isY) {                                                                 \
      int wt = (W0) <= 124 ? (W0) : 124;                                       \
      _Pragma("unroll")                                                        \
      for (int i = 0; i < 4; ++i) {                                            \
        SA[i] = *(const float4*)(pbase + (size_t)(m0 + i) * 8192 + wt);        \
        SB[i] = *(const float4*)(pbase + (size_t)(m1 + i) * 8192 + wt);        \
      }                                                                        \
    }                                                                          \
  } while (0)

    STEP(pY0, sm.cy[1], pA, pB, y);
    STEP(pY1, sm.cy[0], pA, pB, z);
    STEP(pY0, sm.cy[1], pA, pB, w);
    REFILL(pA, pB, 8);

    int w0 = 4;
#pragma unroll 1
    for (int it = 0; it < 15; ++it) {
      STEP(pY1, sm.cy[0], qA, qB, x);
      STEP(pY0, sm.cy[1], qA, qB, y);
      STEP(pY1, sm.cy[0], qA, qB, z);
      STEP(pY0, sm.cy[1], qA, qB, w);
      REFILL(qA, qB, w0 + 8);
      STEP(pY1, sm.cy[0], pA, pB, x);
      STEP(pY0, sm.cy[1], pA, pB, y);
      STEP(pY1, sm.cy[0], pA, pB, z);
      STEP(pY0, sm.cy[1], pA, pB, w);
      REFILL(pA, pB, w0 + 12);
      w0 += 8;
    }

    STEP(pY1, sm.cy[0], qA, qB, x);
    STEP(pY0, sm.cy[1], qA, qB, y);
    STEP(pY1, sm.cy[0], qA, qB, z);
    STEP(pY0, sm.cy[1], qA, qB, w);
#undef STEP
#undef REFILL

    // s[b,h,127-w] = dot(v, z_w): 4 threads per w, 64 channels each
    {
      const int w    = tid >> 2;
      const int part = tid & 3;
      const _Float16* zr = sm.zh + w * 256 + part * 64;
      const float*    vr = conv1 + part * 64;
      float s = 0.f;
#pragma unroll
      for (int j = 0; j < 8; ++j) {
        f16x8 zv = *(const f16x8*)(zr + j * 8);
        float4 v0 = *(const float4*)(vr + j * 8);
        float4 v1 = *(const float4*)(vr + j * 8 + 4);
        s += v0.x * (float)zv[0] + v0.y * (float)zv[1]
           + v0.z * (float)zv[2] + v0.w * (float)zv[3]
           + v1.x * (float)zv[4] + v1.y * (float)zv[5]
           + v1.z * (float)zv[6] + v1.w * (float)zv[7];
      }
      s += __shfl_xor(s, 1, 64);
      s += __shfl_xor(s, 2, 64);
      if (part == 0) sout[(blockIdx.x << 7) + (127 - w)] = s;
    }
  }
  gbar(cnt + 1, tid, 256);

  // ---- phase 3: stats over upsampled field (u kept in registers) ----------
  int base = blockIdx.x * 1024 + tid;
  float u0 = bilin(sout, base);
  float u1 = bilin(sout, base + 512);
  {
    float sum = u0 + u1, ssq = u0 * u0 + u1 * u1;
#pragma unroll
    for (int off = 32; off > 0; off >>= 1) {
      sum += __shfl_xor(sum, off, 64);
      ssq += __shfl_xor(ssq, off, 64);
    }
    int wv = tid >> 6;
    if ((tid & 63) == 0) { ls[wv] = sum; lq[wv] = ssq; }
    __syncthreads();
    if (tid == 0) {
      float ts = 0.f, tq = 0.f;
#pragma unroll
      for (int i = 0; i < 8; ++i) { ts += ls[i]; tq += lq[i]; }
      atomicAdd(&stats[0], ts);
      atomicAdd(&stats[1], tq);
    }
  }
  gbar(cnt + 2, tid, 256);

  // ---- phase 4: normalize + sigmoid (stats via coherent atomic read) ------
  if (tid == 0) {
    sb2[0] = atomicAdd(&stats[0], 0.f);
    sb2[1] = atomicAdd(&stats[1], 0.f);
  }
  __syncthreads();
  {
    const float invN = 1.f / 262144.f;
    float mean  = sb2[0] * invN;
    float var   = sb2[1] * invN - mean * mean;
    float scale = rsqrtf(var + 1e-5f) * gamma[0];
    float bias  = beta[0] - mean * scale;
    float x0 = u0 * scale + bias;
    float x1 = u1 * scale + bias;
    out[base]       = 1.f / (1.f + __expf(-x0));
    out[base + 512] = 1.f / (1.f + __expf(-x1));
  }
}

// ---------------------------------------------------------------------------
extern "C" void kernel_launch(void* const* d_in, const int* in_sizes, int n_in,
                              void* d_out, int out_size, void* d_ws, size_t ws_size,
                              hipStream_t stream) {
  const float* p2    = (const float*)d_in[0];   // (2,256,64,128)
  const float* convw = (const float*)d_in[1];   // (256,256,1,9)
  const float* conv1 = (const float*)d_in[2];   // (1,256,1,1)
  const float* gamma = (const float*)d_in[3];   // (1,)
  const float* beta  = (const float*)d_in[4];   // (1,)
  float* out = (float*)d_out;                   // (2,1,256,512) fp32

  char* ws = (char*)d_ws;
  float*    s     = (float*)ws;                 // 16384 floats  [0, 64KB)
  float*    stats = (float*)(ws + 65536);       // 2 floats
  int*      cnt   = (int*)(ws + 65664);         // 3 barrier counters
  _Float16* Md    = (_Float16*)(ws + 65792);    // 65536 f16 (128 KB)

  // zero stats + barrier counters (stream-ordered, graph-capture-safe)
  hipMemsetAsync(ws + 65536, 0, 192, stream);
  hipLaunchKernelGGL(k_fused, dim3(256), dim3(512), 0, stream,
                     p2, convw, conv1, gamma, beta, out, Md, s, stats, cnt);
}

// Round 10
// 179.081 us; speedup vs baseline: 1.2344x; 1.2344x over previous
//
#include <hip/hip_runtime.h>

// ---------------------------------------------------------------------------
// R_SCNN: two width-direction SCNN scans fused into one 127-step recurrence,
// executed with MFMA, ONE barrier per step, then 4x bilinear upsample +
// global BN + sigmoid.
//
//   y_w = c_w + relu(M y_{w-1}),  z_w = y_w + relu(M z_{w-1}),  z_0 = y_0 = c_0
//   s[b,h,p] = dot(v, z_{127-p});  out = sigmoid(BN(upsample4(s)))
//
// Round-14: R8 base (best measured: 176.6us; k_scan 103.5us) + analytic
// k_stats. R9's mega-kernel proved the ~50us outside kernel time is FIXED
// harness overhead (2 dispatches vs 4 dispatches: same ~50us residual), so
// launch-count fusion is a dead end; only kernel-time-sum matters.
// k_stats change: upsample is separable-linear, so the BN sums are exact
// quadratic forms over the 64KB s field:
//   sum(u)  = sum_y CY[y] * dot(s[y], CX)
//   sum(u2) = sum_y DYY[y]*B2(s[y],s[y]) + sum_y DYZ[y]*B2(s[y],s[y+1])
//   B2(u,v) = sum_x CXX[x] u v + 0.5*sum_x CXY[x] (u[x]v[x+1]+u[x+1]v[x])
// with CX/CXX/CXY (x-direction) and CY/DYY/DYZ (y-direction) accumulated
// from the SAME fy/fx formulas bilin uses. One 256-thread block, ~130K
// FLOPs, no atomics; emits scale/bias directly so k_norm loads 2 floats.
// Scan kernel untouched (its ~800ns/step floor is the barriered exchange
// round-trip at the ~1.6GHz clock this low-util kernel gets; ledger: fewer
// waves worse R2, less DS data null R5, stagger worse R3/R6, fusion worse
// R7/R9, prefetch streamlining -60cy R7).
// ---------------------------------------------------------------------------

typedef _Float16 f16x8 __attribute__((ext_vector_type(8)));
typedef _Float16 f16x4 __attribute__((ext_vector_type(4)));
typedef float    f32x4 __attribute__((ext_vector_type(4)));

// Raw workgroup barrier: drain LDS ops only; global (vmcnt) loads stay in
// flight across it.
static __device__ __forceinline__ void sync_lds() {
  asm volatile("s_waitcnt lgkmcnt(0)" ::: "memory");
  __builtin_amdgcn_s_barrier();
  asm volatile("" ::: "memory");
}

// quad_perm(0,0,2,2): lane 2k+1 receives lane 2k's value (VALU-speed, no LDS)
static __device__ __forceinline__ float dpp_even(float v) {
  int t = __builtin_bit_cast(int, v);
  t = __builtin_amdgcn_update_dpp(t, t, 0xA0, 0xF, 0xF, false);
  return __builtin_bit_cast(float, t);
}

// ---- kernel 0: extract center tap of conv_w -> dense f16 [o][c], coalesced -
extern "C" __global__ void k_extract(const float* __restrict__ convw,
                                     _Float16* __restrict__ Md) {
  int q = blockIdx.x * 256 + threadIdx.x;   // 147456 float4s = 589824 floats
  float4 v = ((const float4*)convw)[q];
  float vv[4] = {v.x, v.y, v.z, v.w};
  int f = q * 4;
#pragma unroll
  for (int e = 0; e < 4; ++e) {
    int flat = f + e;                       // flat = idx*9 + 4  <=>  center tap
    if (flat % 9 == 4) Md[flat / 9] = (_Float16)vv[e];
  }
}

// ---- kernel 1: fused double scan via MFMA ---------------------------------
struct SM {
  _Float16 cy[2][256];     // y carry (f16), ping-pong            [byte 0)
  _Float16 pad_[32];       // 64B: shifts z rows' banks by 16 vs cy
  _Float16 zh[128 * 256];  // z history; row w = z_w (also z carry) [byte 1088)
};

extern "C" __global__ void __launch_bounds__(512, 1)
k_scan(const float* __restrict__ p2, const _Float16* __restrict__ Md,
       const float* __restrict__ conv1, float* __restrict__ sout) {
  __shared__ SM sm;
  const int tid  = threadIdx.x;
  const int l    = tid & 63;
  const int r    = tid >> 6;        // wave 0..7
  const int col  = l & 15;          // MFMA n / A-row-within-tile index
  const int quad = l >> 4;          // MFMA k-group / C-row-group index
  const int b    = blockIdx.x >> 6;
  const int h    = blockIdx.x & 63;

  const bool isY   = (col == 0);    // lanes holding C column 0 (y results)
  const bool isZ   = (col == 1);    // lanes holding C column 1 (z results)
  const bool zlane = (l & 1);       // odd cols read the z stream as B

  // C/D rows owned by this lane: m0..m0+3 (tile 0), m1..m1+3 (tile 1)
  const int m0 = (r * 2 + 0) * 16 + quad * 4;
  const int m1 = (r * 2 + 1) * 16 + quad * 4;

  // A-fragments (M matrix, AGPR-resident): A[m=t*16+col][k=ch*32+quad*8+j]
  f16x8 A0[8], A1[8];
#pragma unroll
  for (int ch = 0; ch < 8; ++ch) {
    A0[ch] = *(const f16x8*)(Md + ((r*2+0)*16 + col) * 256 + ch*32 + quad*8);
    A1[ch] = *(const f16x8*)(Md + ((r*2+1)*16 + col) * 256 + ch*32 + quad*8);
  }

  // p2_r[b][c][h][w]: channel c at pbase + c*8192 + w
  const float* pbase = p2 + (size_t)b * 2097152 + (size_t)h * 128;

  // float4 c-pipeline (isY lanes): set p covers w-block 4j (j even), set q
  // covers 4j (j odd). Each float4 = c at [row][w0..w0+3]; 16B aligned.
  float4 pA[4], pB[4], qA[4], qB[4];
  if (isY) {
#pragma unroll
    for (int i = 0; i < 4; ++i) {
      pA[i] = *(const float4*)(pbase + (size_t)(m0 + i) * 8192);
      pB[i] = *(const float4*)(pbase + (size_t)(m1 + i) * 8192);
      qA[i] = *(const float4*)(pbase + (size_t)(m0 + i) * 8192 + 4);
      qB[i] = *(const float4*)(pbase + (size_t)(m1 + i) * 8192 + 4);
    }
  }

  // init: w=0 state (z_0 = y_0 = c_0) into cy[0] and zh row 0 (c_0 = pX.x)
  if (isY) {
    f16x4 pa, pb;
#pragma unroll
    for (int i = 0; i < 4; ++i) {
      pa[i] = (_Float16)pA[i].x; pb[i] = (_Float16)pB[i].x;
    }
    *(f16x4*)(sm.cy[0] + m0) = pa; *(f16x4*)(sm.cy[0] + m1) = pb;
    *(f16x4*)(sm.zh    + m0) = pa; *(f16x4*)(sm.zh    + m1) = pb;
  }
  sync_lds();

  // B-fragment sources: even cols read y ping-pong, odd cols read z history.
  const _Float16* pY0 = sm.cy[0] + quad * 8;   // read on odd steps
  const _Float16* pY1 = sm.cy[1] + quad * 8;   // read on even steps
  const _Float16* zrd = sm.zh + quad * 8;      // row w-1; +256/step
  _Float16*       zwr = sm.zh + 256;           // row w;   +256/step

  // STEP: one recurrence step. COMP picks the float4 member (w&3).
#define STEP(PY, WY, CA, CB, COMP)                                             \
  do {                                                                         \
    const _Float16* bsrc = zlane ? zrd : (PY);                                 \
    f16x8 B[8];                                                                \
    _Pragma("unroll")                                                          \
    for (int ch = 0; ch < 8; ++ch)                                             \
      B[ch] = *(const f16x8*)(bsrc + ch * 32);                                 \
    f32x4 a00 = {0.f,0.f,0.f,0.f}, a01 = {0.f,0.f,0.f,0.f};                    \
    f32x4 a10 = {0.f,0.f,0.f,0.f}, a11 = {0.f,0.f,0.f,0.f};                    \
    _Pragma("unroll")                                                          \
    for (int ch = 0; ch < 4; ++ch) {                                           \
      a00 = __builtin_amdgcn_mfma_f32_16x16x32_f16(A0[ch],   B[ch],   a00,0,0,0);\
      a10 = __builtin_amdgcn_mfma_f32_16x16x32_f16(A1[ch],   B[ch],   a10,0,0,0);\
      a01 = __builtin_amdgcn_mfma_f32_16x16x32_f16(A0[ch+4], B[ch+4], a01,0,0,0);\
      a11 = __builtin_amdgcn_mfma_f32_16x16x32_f16(A1[ch+4], B[ch+4], a11,0,0,0);\
    }                                                                          \
    f32x4 acc0 = a00 + a01, acc1 = a10 + a11;                                  \
    f32x4 yf0 = {}, yf1 = {};                                                  \
    if (isY) {                                                                 \
      f16x4 yh0, yh1;                                                          \
      _Pragma("unroll")                                                        \
      for (int i = 0; i < 4; ++i) {                                            \
        yf0[i] = (CA)[i].COMP + fmaxf(acc0[i], 0.f);                           \
        yf1[i] = (CB)[i].COMP + fmaxf(acc1[i], 0.f);                           \
        yh0[i] = (_Float16)yf0[i]; yh1[i] = (_Float16)yf1[i];                  \
      }                                                                        \
      *(f16x4*)((WY) + m0) = yh0;                                              \
      *(f16x4*)((WY) + m1) = yh1;                                              \
    }                                                                          \
    _Pragma("unroll")                                                          \
    for (int i = 0; i < 4; ++i) {                                              \
      yf0[i] = dpp_even(yf0[i]);                                               \
      yf1[i] = dpp_even(yf1[i]);                                               \
    }                                                                          \
    if (isZ) {                                                                 \
      f16x4 zh0, zh1;                                                          \
      _Pragma("unroll")                                                        \
      for (int i = 0; i < 4; ++i) {                                            \
        zh0[i] = (_Float16)(yf0[i] + fmaxf(acc0[i], 0.f));                     \
        zh1[i] = (_Float16)(yf1[i] + fmaxf(acc1[i], 0.f));                     \
      }                                                                        \
      *(f16x4*)(zwr + m0) = zh0;                                               \
      *(f16x4*)(zwr + m1) = zh1;                                               \
    }                                                                          \
    zrd += 256; zwr += 256;                                                    \
    sync_lds();                                                                \
  } while (0)

  // REFILL: reload a float4 set for w-block starting at W0 (clamped so the
  // float4 stays in-bounds; clamped dups are never consumed).
#define REFILL(SA, SB, W0)                                                     \
  do {                                                                         \
    if (isY) {                                                                 \
      int wt = (W0) <= 124 ? (W0) : 124;                                       \
      _Pragma("unroll")                                                        \
      for (int i = 0; i < 4; ++i) {                                            \
        SA[i] = *(const float4*)(pbase + (size_t)(m0 + i) * 8192 + wt);        \
        SB[i] = *(const float4*)(pbase + (size_t)(m1 + i) * 8192 + wt);        \
      }                                                                        \
    }                                                                          \
  } while (0)

  // prologue steps w = 1,2,3 (set p, comps 1..3), then refill p for w=8..11
  STEP(pY0, sm.cy[1], pA, pB, y);
  STEP(pY1, sm.cy[0], pA, pB, z);
  STEP(pY0, sm.cy[1], pA, pB, w);
  REFILL(pA, pB, 8);

  // main: 15 iterations x 8 steps cover w = 4..123
  int w0 = 4;
#pragma unroll 1
  for (int it = 0; it < 15; ++it) {
    STEP(pY1, sm.cy[0], qA, qB, x);   // w0+0 (even)
    STEP(pY0, sm.cy[1], qA, qB, y);   // w0+1
    STEP(pY1, sm.cy[0], qA, qB, z);   // w0+2
    STEP(pY0, sm.cy[1], qA, qB, w);   // w0+3
    REFILL(qA, qB, w0 + 8);
    STEP(pY1, sm.cy[0], pA, pB, x);   // w0+4
    STEP(pY0, sm.cy[1], pA, pB, y);   // w0+5
    STEP(pY1, sm.cy[0], pA, pB, z);   // w0+6
    STEP(pY0, sm.cy[1], pA, pB, w);   // w0+7
    REFILL(pA, pB, w0 + 12);
    w0 += 8;
  }

  // tail: w = 124..127 (set q)
  STEP(pY1, sm.cy[0], qA, qB, x);
  STEP(pY0, sm.cy[1], qA, qB, y);
  STEP(pY1, sm.cy[0], qA, qB, z);
  STEP(pY0, sm.cy[1], qA, qB, w);
#undef STEP
#undef REFILL

  // s[b,h,127-w] = dot(v, z_w): 4 threads per w, 64 channels each
  {
    const int w    = tid >> 2;
    const int part = tid & 3;
    const _Float16* zr = sm.zh + w * 256 + part * 64;
    const float*    vr = conv1 + part * 64;
    float s = 0.f;
#pragma unroll
    for (int j = 0; j < 8; ++j) {
      f16x8 zv = *(const f16x8*)(zr + j * 8);
      float4 v0 = *(const float4*)(vr + j * 8);
      float4 v1 = *(const float4*)(vr + j * 8 + 4);
      s += v0.x * (float)zv[0] + v0.y * (float)zv[1]
         + v0.z * (float)zv[2] + v0.w * (float)zv[3]
         + v1.x * (float)zv[4] + v1.y * (float)zv[5]
         + v1.z * (float)zv[6] + v1.w * (float)zv[7];
    }
    s += __shfl_xor(s, 1, 64);
    s += __shfl_xor(s, 2, 64);
    if (part == 0) sout[(blockIdx.x << 7) + (127 - w)] = s;
  }
}

// ---- bilinear 4x upsample (align_corners) of s: (2,64,128) -> (2,256,512) --
static __device__ __forceinline__ float bilin(const float* __restrict__ s,
                                              int idx) {
  int bb  = idx >> 17;
  int rem = idx & 131071;
  int ho  = rem >> 9;
  int wo  = rem & 511;
  const float SY = 63.0f / 255.0f, SX = 127.0f / 511.0f;
  float fy = (float)ho * SY;
  int y0 = (int)fy; int y1 = min(y0 + 1, 63); float wy = fy - (float)y0;
  float fx = (float)wo * SX;
  int x0 = (int)fx; int x1 = min(x0 + 1, 127); float wx = fx - (float)x0;
  const float* sb = s + bb * 8192;
  float cA = sb[y0 * 128 + x0] * (1.f - wy) + sb[y1 * 128 + x0] * wy;
  float cB = sb[y0 * 128 + x1] * (1.f - wy) + sb[y1 * 128 + x1] * wy;
  return cA * (1.f - wx) + cB * wx;
}

// ---- kernel 2: analytic BN stats (single block) ---------------------------
// Upsample is separable-linear, so the global sums over the upsampled field
// are exact quadratic forms over s (64KB). Weight accumulation uses the SAME
// fy/fx formulas as bilin, so coverage/rounding match the reference exactly.
// Emits stats[0]=scale, stats[1]=bias directly.
extern "C" __global__ void k_stats(const float* __restrict__ s,
                                   const float* __restrict__ gamma,
                                   const float* __restrict__ beta,
                                   float* __restrict__ stats) {
  __shared__ float CX[128], CXX[128], CXY[128];
  __shared__ float CY[64],  DYY[64],  DYZ[64];
  __shared__ float P[128], Rr[128], C2[126];
  __shared__ float w1[4], w2[4];
  const int tid = threadIdx.x;
  const float SY = 63.0f / 255.0f, SX = 127.0f / 511.0f;

  // x-direction weights: thread x scans the ~12 wo that can touch bucket x
  if (tid < 128) {
    const int x = tid;
    float cx = 0.f, cxx = 0.f, cxy = 0.f;
    int lo = (x - 1) * 511 / 127 - 2; if (lo < 0) lo = 0;
    int hi = (x + 1) * 511 / 127 + 2; if (hi > 511) hi = 511;
    for (int wo = lo; wo <= hi; ++wo) {
      float fx = (float)wo * SX;
      int x0 = (int)fx; int x1 = min(x0 + 1, 127); float wx = fx - (float)x0;
      if (x0 == x) {
        float a = 1.f - wx;
        cx += a; cxx += a * a;
        if (x1 == x + 1) cxy += 2.f * a * wx;
      }
      if (x1 == x && x0 == x - 1) { cx += wx; cxx += wx * wx; }
    }
    CX[x] = cx; CXX[x] = cxx; CXY[x] = cxy;
  } else if (tid < 192) {
    // y-direction weights
    const int y = tid - 128;
    float cy = 0.f, dyy = 0.f, dyz = 0.f;
    int lo = (y - 1) * 255 / 63 - 2; if (lo < 0) lo = 0;
    int hi = (y + 1) * 255 / 63 + 2; if (hi > 255) hi = 255;
    for (int ho = lo; ho <= hi; ++ho) {
      float fy = (float)ho * SY;
      int y0 = (int)fy; int y1 = min(y0 + 1, 63); float wy = fy - (float)y0;
      if (y0 == y) {
        float a = 1.f - wy;
        cy += a; dyy += a * a;
        if (y1 == y + 1) dyz += 2.f * a * wy;
      }
      if (y1 == y && y0 == y - 1) { cy += wy; dyy += wy * wy; }
    }
    CY[y] = cy; DYY[y] = dyy; DYZ[y] = dyz;
  }
  __syncthreads();

  // per-row linear/quadratic forms over s
  if (tid < 128) {
    const float* row = s + (tid >> 6) * 8192 + (tid & 63) * 128;
    float p = 0.f, rr = 0.f;
    for (int x = 0; x < 127; ++x) {
      p  += CXX[x] * row[x] * row[x] + CXY[x] * row[x] * row[x + 1];
      rr += CX[x] * row[x];
    }
    p  += CXX[127] * row[127] * row[127];
    rr += CX[127] * row[127];
    P[tid] = p; Rr[tid] = rr;
  } else if (tid < 254) {
    const int k  = tid - 128;        // 0..125
    const int bb = (k >= 63);
    const int y  = k - 63 * bb;
    const float* u = s + bb * 8192 + y * 128;
    const float* v = u + 128;
    float c = 0.f;
    for (int x = 0; x < 127; ++x)
      c += CXX[x] * u[x] * v[x]
         + 0.5f * CXY[x] * (u[x] * v[x + 1] + u[x + 1] * v[x]);
    c += CXX[127] * u[127] * v[127];
    C2[k] = c;
  }
  __syncthreads();

  // combine with y-weights and reduce
  float s1 = 0.f, s2 = 0.f;
  if (tid < 128) {
    const int bb = tid >> 6, y = tid & 63;
    s1 = CY[y] * Rr[tid];
    s2 = DYY[y] * P[tid];
    if (y < 63) s2 += DYZ[y] * C2[bb * 63 + y];
  }
#pragma unroll
  for (int off = 32; off > 0; off >>= 1) {
    s1 += __shfl_xor(s1, off, 64);
    s2 += __shfl_xor(s2, off, 64);
  }
  if ((tid & 63) == 0) { w1[tid >> 6] = s1; w2[tid >> 6] = s2; }
  __syncthreads();
  if (tid == 0) {
    float S1 = w1[0] + w1[1] + w1[2] + w1[3];
    float S2 = w2[0] + w2[1] + w2[2] + w2[3];
    const float invN = 1.f / 262144.f;
    float mean  = S1 * invN;
    float var   = S2 * invN - mean * mean;
    float scale = rsqrtf(var + 1e-5f) * gamma[0];
    stats[0] = scale;
    stats[1] = beta[0] - mean * scale;
  }
}

// ---- kernel 3: normalize + sigmoid -----------------------------------------
extern "C" __global__ void k_norm(const float* __restrict__ s,
                                  const float* __restrict__ stats,
                                  float* __restrict__ out) {
  int tid  = threadIdx.x;
  int base = blockIdx.x * 1024 + tid;
  float scale = stats[0];
  float bias  = stats[1];
#pragma unroll
  for (int i = 0; i < 4; ++i) {
    int idx = base + i * 256;
    float u = bilin(s, idx);
    float x = u * scale + bias;
    out[idx] = 1.f / (1.f + __expf(-x));
  }
}

// ---------------------------------------------------------------------------
extern "C" void kernel_launch(void* const* d_in, const int* in_sizes, int n_in,
                              void* d_out, int out_size, void* d_ws, size_t ws_size,
                              hipStream_t stream) {
  const float* p2    = (const float*)d_in[0];   // (2,256,64,128)
  const float* convw = (const float*)d_in[1];   // (256,256,1,9)
  const float* conv1 = (const float*)d_in[2];   // (1,256,1,1)
  const float* gamma = (const float*)d_in[3];   // (1,)
  const float* beta  = (const float*)d_in[4];   // (1,)
  float* out = (float*)d_out;                   // (2,1,256,512) fp32

  char* ws = (char*)d_ws;
  float*    s     = (float*)ws;                 // 16384 floats  [0, 64KB)
  float*    stats = (float*)(ws + 65536);       // scale, bias
  _Float16* Md    = (_Float16*)(ws + 65792);    // 65536 f16 (128 KB)

  hipLaunchKernelGGL(k_extract, dim3(576), dim3(256), 0, stream, convw, Md);
  hipLaunchKernelGGL(k_scan,    dim3(128), dim3(512), 0, stream, p2, Md, conv1, s);
  hipLaunchKernelGGL(k_stats,   dim3(1),   dim3(256), 0, stream, s, gamma, beta, stats);
  hipLaunchKernelGGL(k_norm,    dim3(256), dim3(256), 0, stream, s, stats, out);
}

// Round 11
// 176.104 us; speedup vs baseline: 1.2553x; 1.0169x over previous
//
#include <hip/hip_runtime.h>

// ---------------------------------------------------------------------------
// R_SCNN: two width-direction SCNN scans fused into one 127-step recurrence,
// executed with MFMA, ONE barrier per step, then 4x bilinear upsample +
// global BN + sigmoid.
//
//   y_w = c_w + relu(M y_{w-1}),  z_w = y_w + relu(M z_{w-1}),  z_0 = y_0 = c_0
//   s[b,h,p] = dot(v, z_{127-p});  out = sigmoid(BN(upsample4(s)))
//
// Round-15 (FINAL consolidation = R8, best measured 176.55us):
//  k_scan (103.5us): 8 waves x 2 row-tiles, raw lgkm-only barrier (global
//  prefetch stays in flight), float4 c-prefetch ping-pong (covers 4 steps
//  per reload, issued with ~4-step slack), DPP quad_perm y->z handoff,
//  z-history in LDS + post-loop parallel s-dot, launch_bounds(512,1).
//
//  Evidence ledger (10 rounds of discriminators):
//   - vmcnt-drain fix + DPP + off-path dot: -7.7us (kept)
//   - float4 c-prefetch + 256-reg budget:   -3us   (kept)
//   - fewer waves (R2): WORSE (latency-serialization, not DS throughput)
//   - exec-masked B reads (R5): NULL (not DS-return-bound)
//   - antiphase stagger (R3/R6): WORSE (half-work phase ~= full step)
//   - in-kernel grid-sync fusion (R7/R9): WORSE (cross-XCD coherence cost;
//     ~50us residual is FIXED harness overhead, not per-launch gaps)
//   - analytic quadratic-form stats (R10): NULL (1-block serialization)
//  Step floor ~820ns = algorithmic: each step mixes all 256 channels, the
//  carry spans 8 waves, so one LDS exchange + barrier per step is
//  structural; all pipes <25% busy at that floor.
// ---------------------------------------------------------------------------

typedef _Float16 f16x8 __attribute__((ext_vector_type(8)));
typedef _Float16 f16x4 __attribute__((ext_vector_type(4)));
typedef float    f32x4 __attribute__((ext_vector_type(4)));

// Raw workgroup barrier: drain LDS ops only; global (vmcnt) loads stay in
// flight across it.
static __device__ __forceinline__ void sync_lds() {
  asm volatile("s_waitcnt lgkmcnt(0)" ::: "memory");
  __builtin_amdgcn_s_barrier();
  asm volatile("" ::: "memory");
}

// quad_perm(0,0,2,2): lane 2k+1 receives lane 2k's value (VALU-speed, no LDS)
static __device__ __forceinline__ float dpp_even(float v) {
  int t = __builtin_bit_cast(int, v);
  t = __builtin_amdgcn_update_dpp(t, t, 0xA0, 0xF, 0xF, false);
  return __builtin_bit_cast(float, t);
}

// ---- kernel 0: extract center tap of conv_w -> dense f16 [o][c], coalesced -
extern "C" __global__ void k_extract(const float* __restrict__ convw,
                                     _Float16* __restrict__ Md) {
  int q = blockIdx.x * 256 + threadIdx.x;   // 147456 float4s = 589824 floats
  float4 v = ((const float4*)convw)[q];
  float vv[4] = {v.x, v.y, v.z, v.w};
  int f = q * 4;
#pragma unroll
  for (int e = 0; e < 4; ++e) {
    int flat = f + e;                       // flat = idx*9 + 4  <=>  center tap
    if (flat % 9 == 4) Md[flat / 9] = (_Float16)vv[e];
  }
}

// ---- kernel 1: fused double scan via MFMA ---------------------------------
struct SM {
  _Float16 cy[2][256];     // y carry (f16), ping-pong            [byte 0)
  _Float16 pad_[32];       // 64B: shifts z rows' banks by 16 vs cy
  _Float16 zh[128 * 256];  // z history; row w = z_w (also z carry) [byte 1088)
};

extern "C" __global__ void __launch_bounds__(512, 1)
k_scan(const float* __restrict__ p2, const _Float16* __restrict__ Md,
       const float* __restrict__ conv1, float* __restrict__ sout,
       float* __restrict__ stats) {
  __shared__ SM sm;
  const int tid  = threadIdx.x;
  const int l    = tid & 63;
  const int r    = tid >> 6;        // wave 0..7
  const int col  = l & 15;          // MFMA n / A-row-within-tile index
  const int quad = l >> 4;          // MFMA k-group / C-row-group index
  const int b    = blockIdx.x >> 6;
  const int h    = blockIdx.x & 63;

  if (blockIdx.x == 0 && tid == 0) { stats[0] = 0.f; stats[1] = 0.f; }

  const bool isY   = (col == 0);    // lanes holding C column 0 (y results)
  const bool isZ   = (col == 1);    // lanes holding C column 1 (z results)
  const bool zlane = (l & 1);       // odd cols read the z stream as B

  // C/D rows owned by this lane: m0..m0+3 (tile 0), m1..m1+3 (tile 1)
  const int m0 = (r * 2 + 0) * 16 + quad * 4;
  const int m1 = (r * 2 + 1) * 16 + quad * 4;

  // A-fragments (M matrix, AGPR-resident): A[m=t*16+col][k=ch*32+quad*8+j]
  f16x8 A0[8], A1[8];
#pragma unroll
  for (int ch = 0; ch < 8; ++ch) {
    A0[ch] = *(const f16x8*)(Md + ((r*2+0)*16 + col) * 256 + ch*32 + quad*8);
    A1[ch] = *(const f16x8*)(Md + ((r*2+1)*16 + col) * 256 + ch*32 + quad*8);
  }

  // p2_r[b][c][h][w]: channel c at pbase + c*8192 + w
  const float* pbase = p2 + (size_t)b * 2097152 + (size_t)h * 128;

  // float4 c-pipeline (isY lanes): set p covers w-block 4j (j even), set q
  // covers 4j (j odd). Each float4 = c at [row][w0..w0+3]; 16B aligned.
  float4 pA[4], pB[4], qA[4], qB[4];
  if (isY) {
#pragma unroll
    for (int i = 0; i < 4; ++i) {
      pA[i] = *(const float4*)(pbase + (size_t)(m0 + i) * 8192);
      pB[i] = *(const float4*)(pbase + (size_t)(m1 + i) * 8192);
      qA[i] = *(const float4*)(pbase + (size_t)(m0 + i) * 8192 + 4);
      qB[i] = *(const float4*)(pbase + (size_t)(m1 + i) * 8192 + 4);
    }
  }

  // init: w=0 state (z_0 = y_0 = c_0) into cy[0] and zh row 0 (c_0 = pX.x)
  if (isY) {
    f16x4 pa, pb;
#pragma unroll
    for (int i = 0; i < 4; ++i) {
      pa[i] = (_Float16)pA[i].x; pb[i] = (_Float16)pB[i].x;
    }
    *(f16x4*)(sm.cy[0] + m0) = pa; *(f16x4*)(sm.cy[0] + m1) = pb;
    *(f16x4*)(sm.zh    + m0) = pa; *(f16x4*)(sm.zh    + m1) = pb;
  }
  sync_lds();

  // B-fragment sources: even cols read y ping-pong, odd cols read z history.
  const _Float16* pY0 = sm.cy[0] + quad * 8;   // read on odd steps
  const _Float16* pY1 = sm.cy[1] + quad * 8;   // read on even steps
  const _Float16* zrd = sm.zh + quad * 8;      // row w-1; +256/step
  _Float16*       zwr = sm.zh + 256;           // row w;   +256/step

  // STEP: one recurrence step. COMP picks the float4 member (w&3).
#define STEP(PY, WY, CA, CB, COMP)                                             \
  do {                                                                         \
    const _Float16* bsrc = zlane ? zrd : (PY);                                 \
    f16x8 B[8];                                                                \
    _Pragma("unroll")                                                          \
    for (int ch = 0; ch < 8; ++ch)                                             \
      B[ch] = *(const f16x8*)(bsrc + ch * 32);                                 \
    f32x4 a00 = {0.f,0.f,0.f,0.f}, a01 = {0.f,0.f,0.f,0.f};                    \
    f32x4 a10 = {0.f,0.f,0.f,0.f}, a11 = {0.f,0.f,0.f,0.f};                    \
    _Pragma("unroll")                                                          \
    for (int ch = 0; ch < 4; ++ch) {                                           \
      a00 = __builtin_amdgcn_mfma_f32_16x16x32_f16(A0[ch],   B[ch],   a00,0,0,0);\
      a10 = __builtin_amdgcn_mfma_f32_16x16x32_f16(A1[ch],   B[ch],   a10,0,0,0);\
      a01 = __builtin_amdgcn_mfma_f32_16x16x32_f16(A0[ch+4], B[ch+4], a01,0,0,0);\
      a11 = __builtin_amdgcn_mfma_f32_16x16x32_f16(A1[ch+4], B[ch+4], a11,0,0,0);\
    }                                                                          \
    f32x4 acc0 = a00 + a01, acc1 = a10 + a11;                                  \
    f32x4 yf0 = {}, yf1 = {};                                                  \
    if (isY) {                                                                 \
      f16x4 yh0, yh1;                                                          \
      _Pragma("unroll")                                                        \
      for (int i = 0; i < 4; ++i) {                                            \
        yf0[i] = (CA)[i].COMP + fmaxf(acc0[i], 0.f);                           \
        yf1[i] = (CB)[i].COMP + fmaxf(acc1[i], 0.f);                           \
        yh0[i] = (_Float16)yf0[i]; yh1[i] = (_Float16)yf1[i];                  \
      }                                                                        \
      *(f16x4*)((WY) + m0) = yh0;                                              \
      *(f16x4*)((WY) + m1) = yh1;                                              \
    }                                                                          \
    _Pragma("unroll")                                                          \
    for (int i = 0; i < 4; ++i) {                                              \
      yf0[i] = dpp_even(yf0[i]);                                               \
      yf1[i] = dpp_even(yf1[i]);                                               \
    }                                                                          \
    if (isZ) {                                                                 \
      f16x4 zh0, zh1;                                                          \
      _Pragma("unroll")                                                        \
      for (int i = 0; i < 4; ++i) {                                            \
        zh0[i] = (_Float16)(yf0[i] + fmaxf(acc0[i], 0.f));                     \
        zh1[i] = (_Float16)(yf1[i] + fmaxf(acc1[i], 0.f));                     \
      }                                                                        \
      *(f16x4*)(zwr + m0) = zh0;                                               \
      *(f16x4*)(zwr + m1) = zh1;                                               \
    }                                                                          \
    zrd += 256; zwr += 256;                                                    \
    sync_lds();                                                                \
  } while (0)

  // REFILL: reload a float4 set for w-block starting at W0 (clamped so the
  // float4 stays in-bounds; clamped dups are never consumed).
#define REFILL(SA, SB, W0)                                                     \
  do {                                                                         \
    if (isY) {                                                                 \
      int wt = (W0) <= 124 ? (W0) : 124;                                       \
      _Pragma("unroll")                                                        \
      for (int i = 0; i < 4; ++i) {                                            \
        SA[i] = *(const float4*)(pbase + (size_t)(m0 + i) * 8192 + wt);        \
        SB[i] = *(const float4*)(pbase + (size_t)(m1 + i) * 8192 + wt);        \
      }                                                                        \
    }                                                                          \
  } while (0)

  // prologue steps w = 1,2,3 (set p, comps 1..3), then refill p for w=8..11
  STEP(pY0, sm.cy[1], pA, pB, y);
  STEP(pY1, sm.cy[0], pA, pB, z);
  STEP(pY0, sm.cy[1], pA, pB, w);
  REFILL(pA, pB, 8);

  // main: 15 iterations x 8 steps cover w = 4..123
  int w0 = 4;
#pragma unroll 1
  for (int it = 0; it < 15; ++it) {
    STEP(pY1, sm.cy[0], qA, qB, x);   // w0+0 (even)
    STEP(pY0, sm.cy[1], qA, qB, y);   // w0+1
    STEP(pY1, sm.cy[0], qA, qB, z);   // w0+2
    STEP(pY0, sm.cy[1], qA, qB, w);   // w0+3
    REFILL(qA, qB, w0 + 8);
    STEP(pY1, sm.cy[0], pA, pB, x);   // w0+4
    STEP(pY0, sm.cy[1], pA, pB, y);   // w0+5
    STEP(pY1, sm.cy[0], pA, pB, z);   // w0+6
    STEP(pY0, sm.cy[1], pA, pB, w);   // w0+7
    REFILL(pA, pB, w0 + 12);
    w0 += 8;
  }

  // tail: w = 124..127 (set q)
  STEP(pY1, sm.cy[0], qA, qB, x);
  STEP(pY0, sm.cy[1], qA, qB, y);
  STEP(pY1, sm.cy[0], qA, qB, z);
  STEP(pY0, sm.cy[1], qA, qB, w);
#undef STEP
#undef REFILL

  // s[b,h,127-w] = dot(v, z_w): 4 threads per w, 64 channels each
  {
    const int w    = tid >> 2;
    const int part = tid & 3;
    const _Float16* zr = sm.zh + w * 256 + part * 64;
    const float*    vr = conv1 + part * 64;
    float s = 0.f;
#pragma unroll
    for (int j = 0; j < 8; ++j) {
      f16x8 zv = *(const f16x8*)(zr + j * 8);
      float4 v0 = *(const float4*)(vr + j * 8);
      float4 v1 = *(const float4*)(vr + j * 8 + 4);
      s += v0.x * (float)zv[0] + v0.y * (float)zv[1]
         + v0.z * (float)zv[2] + v0.w * (float)zv[3]
         + v1.x * (float)zv[4] + v1.y * (float)zv[5]
         + v1.z * (float)zv[6] + v1.w * (float)zv[7];
    }
    s += __shfl_xor(s, 1, 64);
    s += __shfl_xor(s, 2, 64);
    if (part == 0) sout[(blockIdx.x << 7) + (127 - w)] = s;
  }
}

// ---- bilinear 4x upsample (align_corners) of s: (2,64,128) -> (2,256,512) --
static __device__ __forceinline__ float bilin(const float* __restrict__ s,
                                              int idx) {
  int bb  = idx >> 17;
  int rem = idx & 131071;
  int ho  = rem >> 9;
  int wo  = rem & 511;
  const float SY = 63.0f / 255.0f, SX = 127.0f / 511.0f;
  float fy = (float)ho * SY;
  int y0 = (int)fy; int y1 = min(y0 + 1, 63); float wy = fy - (float)y0;
  float fx = (float)wo * SX;
  int x0 = (int)fx; int x1 = min(x0 + 1, 127); float wx = fx - (float)x0;
  const float* sb = s + bb * 8192;
  float cA = sb[y0 * 128 + x0] * (1.f - wy) + sb[y1 * 128 + x0] * wy;
  float cB = sb[y0 * 128 + x1] * (1.f - wy) + sb[y1 * 128 + x1] * wy;
  return cA * (1.f - wx) + cB * wx;
}

// ---- kernel 2: global sum / sumsq of upsampled field -----------------------
extern "C" __global__ void k_stats(const float* __restrict__ s,
                                   float* __restrict__ stats) {
  int tid  = threadIdx.x;
  int base = blockIdx.x * 1024 + tid;
  float sum = 0.f, ssq = 0.f;
#pragma unroll
  for (int i = 0; i < 4; ++i) {
    float u = bilin(s, base + i * 256);
    sum += u; ssq += u * u;
  }
#pragma unroll
  for (int off = 32; off > 0; off >>= 1) {
    sum += __shfl_xor(sum, off, 64);
    ssq += __shfl_xor(ssq, off, 64);
  }
  __shared__ float ls[4], lq[4];
  int wv = tid >> 6;
  if ((tid & 63) == 0) { ls[wv] = sum; lq[wv] = ssq; }
  __syncthreads();
  if (tid == 0) {
    atomicAdd(&stats[0], ls[0] + ls[1] + ls[2] + ls[3]);
    atomicAdd(&stats[1], lq[0] + lq[1] + lq[2] + lq[3]);
  }
}

// ---- kernel 3: normalize + sigmoid -----------------------------------------
extern "C" __global__ void k_norm(const float* __restrict__ s,
                                  const float* __restrict__ stats,
                                  const float* __restrict__ gamma,
                                  const float* __restrict__ beta,
                                  float* __restrict__ out) {
  int tid  = threadIdx.x;
  int base = blockIdx.x * 1024 + tid;
  const float invN = 1.f / 262144.f;
  float mean  = stats[0] * invN;
  float var   = stats[1] * invN - mean * mean;
  float scale = rsqrtf(var + 1e-5f) * gamma[0];
  float bias  = beta[0] - mean * scale;
#pragma unroll
  for (int i = 0; i < 4; ++i) {
    int idx = base + i * 256;
    float u = bilin(s, idx);
    float x = u * scale + bias;
    out[idx] = 1.f / (1.f + __expf(-x));
  }
}

// ---------------------------------------------------------------------------
extern "C" void kernel_launch(void* const* d_in, const int* in_sizes, int n_in,
                              void* d_out, int out_size, void* d_ws, size_t ws_size,
                              hipStream_t stream) {
  const float* p2    = (const float*)d_in[0];   // (2,256,64,128)
  const float* convw = (const float*)d_in[1];   // (256,256,1,9)
  const float* conv1 = (const float*)d_in[2];   // (1,256,1,1)
  const float* gamma = (const float*)d_in[3];   // (1,)
  const float* beta  = (const float*)d_in[4];   // (1,)
  float* out = (float*)d_out;                   // (2,1,256,512) fp32

  char* ws = (char*)d_ws;
  float*    s     = (float*)ws;                 // 16384 floats  [0, 64KB)
  float*    stats = (float*)(ws + 65536);       // 2 floats
  _Float16* Md    = (_Float16*)(ws + 65792);    // 65536 f16 (128 KB)

  hipLaunchKernelGGL(k_extract, dim3(576), dim3(256), 0, stream, convw, Md);
  hipLaunchKernelGGL(k_scan,    dim3(128), dim3(512), 0, stream, p2, Md, conv1, s, stats);
  hipLaunchKernelGGL(k_stats,   dim3(256), dim3(256), 0, stream, s, stats);
  hipLaunchKernelGGL(k_norm,    dim3(256), dim3(256), 0, stream, s, stats, gamma, beta, out);
}